// Round 4
// baseline (214.477 us; speedup 1.0000x reference)
//
#include <hip/hip_runtime.h>
#include <stdint.h>

// BS=2, QLEN=2048, DIM=1024, NH=16, HD=64
#define BSZ  2
#define SEQ  2048
#define DIM  1024
#define NHD  16
#define HD   64
#define MTOT (BSZ*SEQ)   // 4096

using short8  = __attribute__((ext_vector_type(8))) short;   // 8 bf16
using floatx4 = __attribute__((ext_vector_type(4))) float;   // MFMA C/D

#define QSCALE 0.18033688011112042f   // 0.125 * log2(e): softmax in exp2 domain
#define BIGM   1.44e30f               // mask penalty in exp2 domain

__device__ __forceinline__ unsigned short f2bf(float f) {
    unsigned int u = __float_as_uint(f);
    u += 0x7fffu + ((u >> 16) & 1u);     // RNE
    return (unsigned short)(u >> 16);
}
// pack 2 floats -> 2 bf16 (round-half-up) in 3 VALU ops via v_perm_b32
__device__ __forceinline__ unsigned int pk2r(float a, float b) {
    unsigned int ua = __float_as_uint(a) + 0x8000u;
    unsigned int ub = __float_as_uint(b) + 0x8000u;
    return __builtin_amdgcn_perm(ub, ua, 0x07060302);   // {a_hi16, b_hi16}
}
// pack 2 floats -> 2 bf16 in ONE VALU op (RNE); lo16=bf16(a), hi16=bf16(b)
__device__ __forceinline__ unsigned int cvtpk(float a, float b) {
    unsigned int r;
    asm("v_cvt_pk_bf16_f32 %0, %1, %2" : "=v"(r) : "v"(a), "v"(b));
    return r;
}

// async global->LDS, 16B per lane; dest is wave-uniform base + lane*16.
__device__ __forceinline__ void gll16(const void* g, const void* lds) {
    unsigned int loff = (unsigned int)(unsigned long long)lds;
    __builtin_amdgcn_global_load_lds(
        (const __attribute__((address_space(1))) unsigned int*)g,
        (__attribute__((address_space(3))) unsigned int*)loff, 16, 0, 0);
}

// ---------------------------------------------------------------------------
// fp32 -> bf16 bulk convert (X) + mask -> exp2-domain penalty table (16 KB)
// ---------------------------------------------------------------------------
__global__ __launch_bounds__(256)
void conv_x(const float* __restrict__ X, const float* __restrict__ mask,
            unsigned short* __restrict__ Xbf, float* __restrict__ Pen) {
    size_t i = ((size_t)blockIdx.x * 256 + threadIdx.x) * 8;
    float4 a = *(const float4*)(X + i);
    float4 b = *(const float4*)(X + i + 4);
    uint4 u = {pk2r(a.x, a.y), pk2r(a.z, a.w), pk2r(b.x, b.y), pk2r(b.z, b.w)};
    *(uint4*)(Xbf + i) = u;
    if (blockIdx.x < 2) {   // 2 blocks x 256 thr x 8 = 4096 = MTOT mask floats
        const size_t j = ((size_t)blockIdx.x * 256 + threadIdx.x) * 8;
        float4 m0 = *(const float4*)(mask + j);
        float4 m1 = *(const float4*)(mask + j + 4);
        float4 r0 = {__builtin_fmaf(m0.x, BIGM, -BIGM), __builtin_fmaf(m0.y, BIGM, -BIGM),
                     __builtin_fmaf(m0.z, BIGM, -BIGM), __builtin_fmaf(m0.w, BIGM, -BIGM)};
        float4 r1 = {__builtin_fmaf(m1.x, BIGM, -BIGM), __builtin_fmaf(m1.y, BIGM, -BIGM),
                     __builtin_fmaf(m1.z, BIGM, -BIGM), __builtin_fmaf(m1.w, BIGM, -BIGM)};
        *(float4*)(Pen + j)     = r0;
        *(float4*)(Pen + j + 4) = r1;
    }
}

// ---------------------------------------------------------------------------
// W[k][n] fp32 -> Wt[n][k] bf16  (transpose + convert), 64x64 tiles
// ---------------------------------------------------------------------------
__global__ __launch_bounds__(256)
void conv_wt(const float* __restrict__ Wq, const float* __restrict__ Wk,
             const float* __restrict__ Wv, const float* __restrict__ Wo,
             unsigned short* __restrict__ Wt3, unsigned short* __restrict__ Wto)
{
    __shared__ float tile[64 * 65];
    const int z = blockIdx.z;
    const float* W = (z == 0) ? Wq : (z == 1) ? Wk : (z == 2) ? Wv : Wo;
    unsigned short* out = (z < 3) ? (Wt3 + (size_t)z * DIM * DIM) : Wto;
    const int k0 = blockIdx.x * 64, n0 = blockIdx.y * 64;
    const int t = threadIdx.x;
    const int r = t >> 2, c0 = (t & 3) * 16;
#pragma unroll
    for (int j = 0; j < 4; ++j) {
        float4 v = *(const float4*)&W[(size_t)(k0 + r) * DIM + n0 + c0 + j * 4];
        tile[r * 65 + c0 + j * 4 + 0] = v.x;
        tile[r * 65 + c0 + j * 4 + 1] = v.y;
        tile[r * 65 + c0 + j * 4 + 2] = v.z;
        tile[r * 65 + c0 + j * 4 + 3] = v.w;
    }
    __syncthreads();
    unsigned int p[8];
#pragma unroll
    for (int j = 0; j < 8; ++j)
        p[j] = pk2r(tile[(c0 + 2 * j) * 65 + r], tile[(c0 + 2 * j + 1) * 65 + r]);
    uint4 u0 = {p[0], p[1], p[2], p[3]}, u1 = {p[4], p[5], p[6], p[7]};
    unsigned short* dst = out + (size_t)(n0 + r) * DIM + k0 + c0;
    *(uint4*)dst = u0;
    *(uint4*)(dst + 8) = u1;
}

// ---------------------------------------------------------------------------
// QKV GEMM: 128x128, BK=32, dbuf single-barrier TWO-BODY K-loop.
// XCD-chunked bijective block swizzle: each XCD owns 96 consecutive logical
// blocks = 3 (mat,n0) W-panels x 32 m-tiles -> W panels stay L2-resident.
// Q/K: swapped operands -> packed uint2 stores.  V: transposed sigma layout.
// ---------------------------------------------------------------------------
__global__ __launch_bounds__(256)
void qkv_gemm(const unsigned short* __restrict__ Xbf,
              const unsigned short* __restrict__ Wt3,
              const float* __restrict__ bq, const float* __restrict__ bk,
              const float* __restrict__ bv,
              unsigned short* __restrict__ Qb,
              unsigned short* __restrict__ Kb,
              unsigned short* __restrict__ VbT)
{
    __shared__ unsigned short As[2][128 * 32];
    __shared__ unsigned short Bs[2][128 * 32];

    const int t = threadIdx.x, w = t >> 6, lane = t & 63;
    const int lm = lane & 15, grp = lane >> 4;
    const int wm = w >> 1, wn = w & 1;
    // XCD swizzle: 768 blocks, chunk = 96 per XCD (768 % 8 == 0, bijective)
    const int lin = blockIdx.y * (int)gridDim.x + blockIdx.x;
    const int wg  = (lin & 7) * 96 + (lin >> 3);
    const int m0  = (wg & 31) * 128;
    const int byy = wg >> 5;                     // 0..23
    const int mat = byy >> 3;                    // 0=Q 1=K 2=V
    const int n0  = (byy & 7) * 128;
    const unsigned short* Bg = Wt3 + (size_t)mat * DIM * DIM;
    const int lr = lane >> 2, lc = (lane & 3) * 8;
    const int r0 = w * 16;
    const bool swap = (mat != 2);

    // running stage pointers (advance 32 elems per tile)
    const unsigned short* xs0 = Xbf + (size_t)(m0 + r0 + lr) * DIM + lc;
    const unsigned short* xs1 = Xbf + (size_t)(m0 + 64 + r0 + lr) * DIM + lc;
    const unsigned short* ws0 = Bg  + (size_t)(n0 + r0 + lr) * DIM + lc;
    const unsigned short* ws1 = Bg  + (size_t)(n0 + 64 + r0 + lr) * DIM + lc;

    // hoisted LDS fragment bases (per buffer)
    const unsigned short* afb[2];
    const unsigned short* bfb[2];
#pragma unroll
    for (int u = 0; u < 2; ++u) {
        afb[u] = &As[u][(wm * 64 + lm) * 32 + grp * 8];
        bfb[u] = &Bs[u][(wn * 64 + lm) * 32 + grp * 8];
    }

    floatx4 acc[4][4];
#pragma unroll
    for (int i = 0; i < 4; ++i)
#pragma unroll
        for (int j = 0; j < 4; ++j) acc[i][j] = (floatx4){0.f, 0.f, 0.f, 0.f};

#define QKV_STAGE(BUF) do {                                    \
        gll16(xs0, &As[BUF][r0 * 32]);                         \
        gll16(xs1, &As[BUF][(64 + r0) * 32]);                  \
        gll16(ws0, &Bs[BUF][r0 * 32]);                         \
        gll16(ws1, &Bs[BUF][(64 + r0) * 32]);                  \
        xs0 += 32; xs1 += 32; ws0 += 32; ws1 += 32;            \
    } while (0)

#define QKV_BODY(CUR) do {                                                    \
        __syncthreads();                                                      \
        QKV_STAGE(CUR ^ 1);                                                   \
        short8 af[4], bf[4];                                                  \
        _Pragma("unroll")                                                     \
        for (int mt = 0; mt < 4; ++mt)                                        \
            af[mt] = *(const short8*)(afb[CUR] + mt * 512);                   \
        _Pragma("unroll")                                                     \
        for (int nt = 0; nt < 4; ++nt)                                        \
            bf[nt] = *(const short8*)(bfb[CUR] + nt * 512);                   \
        if (swap) {                                                           \
            _Pragma("unroll")                                                 \
            for (int mt = 0; mt < 4; ++mt)                                    \
                _Pragma("unroll")                                             \
                for (int nt = 0; nt < 4; ++nt)                                \
                    acc[mt][nt] = __builtin_amdgcn_mfma_f32_16x16x32_bf16(    \
                        bf[nt], af[mt], acc[mt][nt], 0, 0, 0);                \
        } else {                                                              \
            _Pragma("unroll")                                                 \
            for (int mt = 0; mt < 4; ++mt)                                    \
                _Pragma("unroll")                                             \
                for (int nt = 0; nt < 4; ++nt)                                \
                    acc[mt][nt] = __builtin_amdgcn_mfma_f32_16x16x32_bf16(    \
                        af[mt], bf[nt], acc[mt][nt], 0, 0, 0);                \
        }                                                                     \
    } while (0)

    QKV_STAGE(0);
#pragma unroll 1
    for (int it = 0; it < DIM / 64; ++it) {   // 16 iterations x 2 bodies
        QKV_BODY(0);
        QKV_BODY(1);
    }
#undef QKV_BODY
#undef QKV_STAGE

    if (mat == 2) {          // V -> sigma-permuted + bank-swizzled [bh][d][s]
#pragma unroll
        for (int nt = 0; nt < 4; ++nt) {
            const int c = n0 + wn * 64 + nt * 16 + lm;
            const float bb = bv[c];
            const int h = c >> 6, d = c & 63;
#pragma unroll
            for (int mt = 0; mt < 4; ++mt) {
                const int r = m0 + wm * 64 + mt * 16 + grp * 4;
                const int b = r >> 11, s = r & 2047;
                const int si = s & 63, sb = s & ~63;
                const int cg = si >> 4, g = (si >> 2) & 3;
                const int unit = (((cg & 1) << 2) | g) ^ (d & 7);   // + bank XOR
                const int sph = sb + unit * 8 + ((cg >> 1) << 2);
                uint2 pv;
                pv.x = pk2r(acc[mt][nt][0] + bb, acc[mt][nt][1] + bb);
                pv.y = pk2r(acc[mt][nt][2] + bb, acc[mt][nt][3] + bb);
                *(uint2*)&VbT[(((size_t)(b * NHD + h)) * HD + d) * SEQ + sph] = pv;
            }
        }
    } else {                 // Q/K swapped epilogue: packed 4-channel stores
        const float* bias = (mat == 0) ? bq : bk;
        unsigned short* dst = (mat == 0) ? Qb : Kb;
        const float sc = (mat == 0) ? QSCALE : 1.0f;
#pragma unroll
        for (int nt = 0; nt < 4; ++nt) {
            const int c0 = n0 + wn * 64 + nt * 16 + grp * 4;   // 4 consecutive c
            float4 bb = *(const float4*)&bias[c0];
            const int h = c0 >> 6, d0 = c0 & 63;
#pragma unroll
            for (int mt = 0; mt < 4; ++mt) {
                const int r = m0 + wm * 64 + mt * 16 + lm;
                const int b = r >> 11, s = r & 2047;
                uint2 pv;
                pv.x = pk2r((acc[mt][nt][0] + bb.x) * sc, (acc[mt][nt][1] + bb.y) * sc);
                pv.y = pk2r((acc[mt][nt][2] + bb.z) * sc, (acc[mt][nt][3] + bb.w) * sc);
                const int dd = (mat == 0) ? d0
                             : ((((d0 >> 3) ^ (s & 7)) << 3) | (d0 & 7));
                *(uint2*)&dst[(((size_t)(b * NHD + h)) * SEQ + s) * HD + dd] = pv;
            }
        }
    }
}

// ---------------------------------------------------------------------------
// Flash attention v13: revert to v11 structure (256 thr, 4 waves, 16 q/wave)
// + THE FIX: mdv (Pen) global loads hoisted ABOVE the gll16 prefetch issues,
// pinned with sched_barrier(0).  vmcnt is a FIFO -- with mdv issued first,
// the QK MFMA waits at vmcnt(8) (mdv only) instead of draining all 8
// prefetches mid-body (an effective vmcnt(0) stall every body since v10).
// Keeps: l-sum via MFMA(ones), setprio, XOR bank swizzle, XCD block swizzle.
// ---------------------------------------------------------------------------
__global__ __launch_bounds__(256, 4)
void attn(const unsigned short* __restrict__ Qb,
          const unsigned short* __restrict__ Kb,
          const unsigned short* __restrict__ VbT,
          const float* __restrict__ Pen,
          unsigned short* __restrict__ Cb)
{
    __shared__ unsigned short Kt[2][64 * 64];  // [key][d_sw]
    __shared__ unsigned short Vt[2][64 * 64];  // [d][key sigma+sw]

    const int t = threadIdx.x, w = t >> 6, lane = t & 63;
    const int lm = lane & 15, grp = lane >> 4;
    const int x7 = lm & 7;

    // XCD swizzle: each XCD gets 128 consecutive logical blocks = 4 heads.
    const int lin = blockIdx.y * (int)gridDim.x + blockIdx.x;   // 0..1023
    const int swz = (lin & 7) * ((SEQ / 64) * (BSZ * NHD) / 8) + (lin >> 3);
    const int bh = swz >> 5, b = bh >> 4, h = bh & 15;
    const int q0 = (swz & 31) * 64;

    // Q B-frags straight from global (n = q = lm, k = d)
    short8 qf[2];
    {
        const unsigned short* qrow = Qb + ((size_t)bh * SEQ + q0 + w * 16 + lm) * HD;
        qf[0] = *(const short8*)(qrow + grp * 8);
        qf[1] = *(const short8*)(qrow + 32 + grp * 8);
    }

    // all-ones bf16 B-frag for the l-sum MFMA
    const unsigned int one2 = 0x3f803f80u;
    uint4 onesu = {one2, one2, one2, one2};
    const short8 ones = *(const short8*)&onesu;

    floatx4 oacc[4];
#pragma unroll
    for (int i = 0; i < 4; ++i) oacc[i] = (floatx4){0.f, 0.f, 0.f, 0.f};
    floatx4 lacc = (floatx4){0.f, 0.f, 0.f, 0.f};

    const unsigned short* Kg = Kb + (size_t)bh * SEQ * HD;
    const unsigned short* Vg = VbT + (size_t)bh * HD * SEQ;
    const int srow = lane >> 3, scol = (lane & 7) * 8;   // gll16 lane mapping

    // running global prefetch pointers
    const unsigned short* kp0 = Kg + (size_t)(w * 16 + srow) * HD + scol;
    const unsigned short* kp1 = kp0 + 8 * HD;
    const unsigned short* vp0 = Vg + (size_t)(w * 16 + srow) * SEQ + scol;
    const unsigned short* vp1 = vp0 + 8 * SEQ;

    // stage tile 0 into buf 0
    gll16(kp0, &Kt[0][(w * 16) * 64]);
    gll16(kp1, &Kt[0][(w * 16 + 8) * 64]);
    gll16(vp0, &Vt[0][(w * 16) * 64]);
    gll16(vp1, &Vt[0][(w * 16 + 8) * 64]);
    kp0 += 64 * HD; kp1 += 64 * HD; vp0 += 64; vp1 += 64;

    // hoisted LDS fragment bases (per buffer); reads use offset immediates
    const unsigned short* kba[2]; const unsigned short* kbb[2];
    const unsigned short* vba[2]; const unsigned short* vbb[2];
#pragma unroll
    for (int u = 0; u < 2; ++u) {
        kba[u] = &Kt[u][lm * 64 + ((grp    ) ^ x7) * 8];
        kbb[u] = &Kt[u][lm * 64 + ((4 + grp) ^ x7) * 8];
        vba[u] = &Vt[u][lm * 64 + ((grp    ) ^ x7) * 8];
        vbb[u] = &Vt[u][lm * 64 + ((4 + grp) ^ x7) * 8];
    }
    const float* mp = Pen + (size_t)b * SEQ + grp * 4;   // advances 64/body

#define ATTN_BODY(CUR) do {                                                   \
        __syncthreads();                                                      \
        float4 mdv[4];                                                        \
        _Pragma("unroll")                                                     \
        for (int cg = 0; cg < 4; ++cg)                                        \
            mdv[cg] = *(const float4*)(mp + cg * 16);                         \
        mp += 64;                                                             \
        __builtin_amdgcn_sched_barrier(0);                                    \
        gll16(kp0, &Kt[CUR ^ 1][(w * 16) * 64]);                              \
        gll16(kp1, &Kt[CUR ^ 1][(w * 16 + 8) * 64]);                          \
        gll16(vp0, &Vt[CUR ^ 1][(w * 16) * 64]);                              \
        gll16(vp1, &Vt[CUR ^ 1][(w * 16 + 8) * 64]);                          \
        kp0 += 64 * HD; kp1 += 64 * HD; vp0 += 64; vp1 += 64;                 \
        floatx4 sv[4];                                                        \
        __builtin_amdgcn_s_setprio(1);                                        \
        _Pragma("unroll")                                                     \
        for (int cg = 0; cg < 4; ++cg) {                                      \
            short8 a0 = *(const short8*)(kba[CUR] + cg * 1024);               \
            short8 a1 = *(const short8*)(kbb[CUR] + cg * 1024);               \
            floatx4 s = (floatx4){mdv[cg].x, mdv[cg].y, mdv[cg].z, mdv[cg].w}; \
            s = __builtin_amdgcn_mfma_f32_16x16x32_bf16(a0, qf[0], s, 0, 0, 0); \
            s = __builtin_amdgcn_mfma_f32_16x16x32_bf16(a1, qf[1], s, 0, 0, 0); \
            sv[cg] = s;                                                       \
        }                                                                     \
        __builtin_amdgcn_s_setprio(0);                                        \
        short8 vf[4][2];                                                      \
        _Pragma("unroll")                                                     \
        for (int dg = 0; dg < 4; ++dg) {                                      \
            vf[dg][0] = *(const short8*)(vba[CUR] + dg * 1024);               \
            vf[dg][1] = *(const short8*)(vbb[CUR] + dg * 1024);               \
        }                                                                     \
        float p[4][4];                                                        \
        _Pragma("unroll")                                                     \
        for (int cg = 0; cg < 4; ++cg) {                                      \
            p[cg][0] = __builtin_exp2f(sv[cg][0]);                            \
            p[cg][1] = __builtin_exp2f(sv[cg][1]);                            \
            p[cg][2] = __builtin_exp2f(sv[cg][2]);                            \
            p[cg][3] = __builtin_exp2f(sv[cg][3]);                            \
        }                                                                     \
        uint4 u0, u1;                                                         \
        u0.x = cvtpk(p[0][0], p[0][1]); u0.y = cvtpk(p[0][2], p[0][3]);       \
        u0.z = cvtpk(p[2][0], p[2][1]); u0.w = cvtpk(p[2][2], p[2][3]);       \
        u1.x = cvtpk(p[1][0], p[1][1]); u1.y = cvtpk(p[1][2], p[1][3]);       \
        u1.z = cvtpk(p[3][0], p[3][1]); u1.w = cvtpk(p[3][2], p[3][3]);       \
        short8 ap0 = *(const short8*)&u0;                                     \
        short8 ap1 = *(const short8*)&u1;                                     \
        __builtin_amdgcn_s_setprio(1);                                        \
        _Pragma("unroll")                                                     \
        for (int dg = 0; dg < 4; ++dg) {                                      \
            oacc[dg] = __builtin_amdgcn_mfma_f32_16x16x32_bf16(ap0, vf[dg][0], oacc[dg], 0, 0, 0); \
            oacc[dg] = __builtin_amdgcn_mfma_f32_16x16x32_bf16(ap1, vf[dg][1], oacc[dg], 0, 0, 0); \
        }                                                                     \
        lacc = __builtin_amdgcn_mfma_f32_16x16x32_bf16(ap0, ones, lacc, 0, 0, 0); \
        lacc = __builtin_amdgcn_mfma_f32_16x16x32_bf16(ap1, ones, lacc, 0, 0, 0); \
        __builtin_amdgcn_s_setprio(0);                                        \
    } while (0)

#pragma unroll 1
    for (int it = 0; it < SEQ / 128; ++it) {   // 16 iterations x 2 bodies
        ATTN_BODY(0);
        ATTN_BODY(1);
    }
#undef ATTN_BODY

    // epilogue: lacc[r] = l for q-row (grp*4+r), identical in every lane col.
    float inv[4];
#pragma unroll
    for (int r = 0; r < 4; ++r) inv[r] = (lacc[r] > 0.f) ? 1.0f / lacc[r] : 0.f;
#pragma unroll
    for (int dg = 0; dg < 4; ++dg)
#pragma unroll
        for (int r = 0; r < 4; ++r) {
            const int s = q0 + w * 16 + grp * 4 + r;
            Cb[((size_t)(b * SEQ + s)) * DIM + h * HD + dg * 16 + lm] =
                f2bf(oacc[dg][r] * inv[r]);
        }
}

// ---------------------------------------------------------------------------
// out = ctx @ Wo + bo: 128Mx64N, dbuf two-body K-loop, swapped operands,
// float4 stores.  XCD-chunked swizzle (512 blocks, chunk=64, bijective).
// ---------------------------------------------------------------------------
__global__ __launch_bounds__(256)
void out_gemm(const unsigned short* __restrict__ Cb,
              const unsigned short* __restrict__ Wto,
              const float* __restrict__ bo,
              float* __restrict__ out)
{
    __shared__ unsigned short As[2][128 * 32];
    __shared__ unsigned short Bs[2][64 * 32];

    const int t = threadIdx.x, w = t >> 6, lane = t & 63;
    const int lm = lane & 15, grp = lane >> 4;
    const int lin = blockIdx.y * (int)gridDim.x + blockIdx.x;   // 0..511
    const int wg  = (lin & 7) * 64 + (lin >> 3);
    const int m0  = (wg & 31) * 128;
    const int n0  = (wg >> 5) * 64;
    const int lr = lane >> 2, lc = (lane & 3) * 8;
    const int r0 = w * 16;

    const unsigned short* cs0 = Cb  + (size_t)(m0 + r0 + lr) * DIM + lc;
    const unsigned short* cs1 = Cb  + (size_t)(m0 + 64 + r0 + lr) * DIM + lc;
    const unsigned short* ws0 = Wto + (size_t)(n0 + r0 + lr) * DIM + lc;

    const unsigned short* afb[2];
    const unsigned short* bfb[2];
#pragma unroll
    for (int u = 0; u < 2; ++u) {
        afb[u] = &As[u][(w * 32 + lm) * 32 + grp * 8];
        bfb[u] = &Bs[u][lm * 32 + grp * 8];
    }

    floatx4 acc[2][4];
#pragma unroll
    for (int i = 0; i < 2; ++i)
#pragma unroll
        for (int j = 0; j < 4; ++j) acc[i][j] = (floatx4){0.f, 0.f, 0.f, 0.f};

#define OUT_STAGE(BUF) do {                                    \
        gll16(cs0, &As[BUF][r0 * 32]);                         \
        gll16(cs1, &As[BUF][(64 + r0) * 32]);                  \
        gll16(ws0, &Bs[BUF][r0 * 32]);                         \
        cs0 += 32; cs1 += 32; ws0 += 32;                       \
    } while (0)

#define OUT_BODY(CUR) do {                                                    \
        __syncthreads();                                                      \
        OUT_STAGE(CUR ^ 1);                                                   \
        short8 af[2], bf[4];                                                  \
        _Pragma("unroll")                                                     \
        for (int mt = 0; mt < 2; ++mt)                                        \
            af[mt] = *(const short8*)(afb[CUR] + mt * 512);                   \
        _Pragma("unroll")                                                     \
        for (int nt = 0; nt < 4; ++nt)                                        \
            bf[nt] = *(const short8*)(bfb[CUR] + nt * 512);                   \
        _Pragma("unroll")                                                     \
        for (int mt = 0; mt < 2; ++mt)                                        \
            _Pragma("unroll")                                                 \
            for (int nt = 0; nt < 4; ++nt)                                    \
                acc[mt][nt] = __builtin_amdgcn_mfma_f32_16x16x32_bf16(        \
                    bf[nt], af[mt], acc[mt][nt], 0, 0, 0);                    \
    } while (0)

    OUT_STAGE(0);
#pragma unroll 1
    for (int it = 0; it < DIM / 64; ++it) {
        OUT_BODY(0);
        OUT_BODY(1);
    }
#undef OUT_BODY
#undef OUT_STAGE

#pragma unroll
    for (int nt = 0; nt < 4; ++nt) {
        const int c0 = n0 + nt * 16 + grp * 4;
        float4 bb = *(const float4*)&bo[c0];
#pragma unroll
        for (int mt = 0; mt < 2; ++mt) {
            const int r = m0 + w * 32 + mt * 16 + lm;
            float4 o = {acc[mt][nt][0] + bb.x, acc[mt][nt][1] + bb.y,
                        acc[mt][nt][2] + bb.z, acc[mt][nt][3] + bb.w};
            *(float4*)&out[(size_t)r * DIM + c0] = o;
        }
    }
}

// ---------------------------------------------------------------------------
extern "C" void kernel_launch(void* const* d_in, const int* in_sizes, int n_in,
                              void* d_out, int out_size, void* d_ws, size_t ws_size,
                              hipStream_t stream)
{
    const float* x    = (const float*)d_in[0];
    const float* mask = (const float*)d_in[1];
    const float* Wq   = (const float*)d_in[2];
    const float* bq   = (const float*)d_in[3];
    const float* Wk   = (const float*)d_in[4];
    const float* bk   = (const float*)d_in[5];
    const float* Wv   = (const float*)d_in[6];
    const float* bv   = (const float*)d_in[7];
    const float* Wo   = (const float*)d_in[8];
    const float* bo   = (const float*)d_in[9];
    float* out = (float*)d_out;

    const size_t M1 = (size_t)DIM * DIM;           // 1M elems
    unsigned short* Qb  = (unsigned short*)d_ws;   // 4M elems each
    unsigned short* Kb  = Qb  + 4 * M1;
    unsigned short* VbT = Kb  + 4 * M1;
    unsigned short* Cb  = VbT + 4 * M1;
    unsigned short* Xbf = Cb  + 4 * M1;
    unsigned short* Wt3 = Xbf + 4 * M1;            // 3M elems
    unsigned short* Wto = Wt3 + 3 * M1;            // 1M elems  (48 MB total)
    float*          Pen = (float*)(Wto + M1);      // MTOT floats (16 KB)

    conv_x <<<dim3((MTOT * DIM) / 2048), 256, 0, stream>>>(x, mask, Xbf, Pen);
    conv_wt<<<dim3(16, 16, 4), 256, 0, stream>>>(Wq, Wk, Wv, Wo, Wt3, Wto);
    qkv_gemm<<<dim3(MTOT / 128, 24), 256, 0, stream>>>(Xbf, Wt3, bq, bk, bv, Qb, Kb, VbT);
    attn<<<dim3(SEQ / 64, BSZ * NHD), 256, 0, stream>>>(Qb, Kb, VbT, Pen, Cb);
    out_gemm<<<dim3(MTOT / 128, DIM / 64), 256, 0, stream>>>(Cb, Wto, bo, out);
}

// Round 5
// 200.236 us; speedup vs baseline: 1.0711x; 1.0711x over previous
//
#include <hip/hip_runtime.h>
#include <stdint.h>

// BS=2, QLEN=2048, DIM=1024, NH=16, HD=64
#define BSZ  2
#define SEQ  2048
#define DIM  1024
#define NHD  16
#define HD   64
#define MTOT (BSZ*SEQ)   // 4096

using short8  = __attribute__((ext_vector_type(8))) short;   // 8 bf16
using floatx4 = __attribute__((ext_vector_type(4))) float;   // MFMA C/D

#define QSCALE 0.18033688011112042f   // 0.125 * log2(e): softmax in exp2 domain
#define BIGM   1.44e30f               // mask penalty in exp2 domain

__device__ __forceinline__ unsigned short f2bf(float f) {
    unsigned int u = __float_as_uint(f);
    u += 0x7fffu + ((u >> 16) & 1u);     // RNE
    return (unsigned short)(u >> 16);
}
// pack 2 floats -> 2 bf16 (round-half-up) in 3 VALU ops via v_perm_b32
__device__ __forceinline__ unsigned int pk2r(float a, float b) {
    unsigned int ua = __float_as_uint(a) + 0x8000u;
    unsigned int ub = __float_as_uint(b) + 0x8000u;
    return __builtin_amdgcn_perm(ub, ua, 0x07060302);   // {a_hi16, b_hi16}
}
// pack 2 floats -> 2 bf16 in ONE VALU op (RNE); lo16=bf16(a), hi16=bf16(b)
__device__ __forceinline__ unsigned int cvtpk(float a, float b) {
    unsigned int r;
    asm("v_cvt_pk_bf16_f32 %0, %1, %2" : "=v"(r) : "v"(a), "v"(b));
    return r;
}

// async global->LDS, 16B per lane; dest is wave-uniform base + lane*16.
__device__ __forceinline__ void gll16(const void* g, const void* lds) {
    unsigned int loff = (unsigned int)(unsigned long long)lds;
    __builtin_amdgcn_global_load_lds(
        (const __attribute__((address_space(1))) unsigned int*)g,
        (__attribute__((address_space(3))) unsigned int*)loff, 16, 0, 0);
}

// ---------------------------------------------------------------------------
// fp32 -> bf16 bulk convert (X) + mask -> exp2-domain penalty table (16 KB)
// ---------------------------------------------------------------------------
__global__ __launch_bounds__(256)
void conv_x(const float* __restrict__ X, const float* __restrict__ mask,
            unsigned short* __restrict__ Xbf, float* __restrict__ Pen) {
    size_t i = ((size_t)blockIdx.x * 256 + threadIdx.x) * 8;
    float4 a = *(const float4*)(X + i);
    float4 b = *(const float4*)(X + i + 4);
    uint4 u = {pk2r(a.x, a.y), pk2r(a.z, a.w), pk2r(b.x, b.y), pk2r(b.z, b.w)};
    *(uint4*)(Xbf + i) = u;
    if (blockIdx.x < 2) {   // 2 blocks x 256 thr x 8 = 4096 = MTOT mask floats
        const size_t j = ((size_t)blockIdx.x * 256 + threadIdx.x) * 8;
        float4 m0 = *(const float4*)(mask + j);
        float4 m1 = *(const float4*)(mask + j + 4);
        float4 r0 = {__builtin_fmaf(m0.x, BIGM, -BIGM), __builtin_fmaf(m0.y, BIGM, -BIGM),
                     __builtin_fmaf(m0.z, BIGM, -BIGM), __builtin_fmaf(m0.w, BIGM, -BIGM)};
        float4 r1 = {__builtin_fmaf(m1.x, BIGM, -BIGM), __builtin_fmaf(m1.y, BIGM, -BIGM),
                     __builtin_fmaf(m1.z, BIGM, -BIGM), __builtin_fmaf(m1.w, BIGM, -BIGM)};
        *(float4*)(Pen + j)     = r0;
        *(float4*)(Pen + j + 4) = r1;
    }
}

// ---------------------------------------------------------------------------
// W[k][n] fp32 -> Wt[n][k] bf16  (transpose + convert), 64x64 tiles
// ---------------------------------------------------------------------------
__global__ __launch_bounds__(256)
void conv_wt(const float* __restrict__ Wq, const float* __restrict__ Wk,
             const float* __restrict__ Wv, const float* __restrict__ Wo,
             unsigned short* __restrict__ Wt3, unsigned short* __restrict__ Wto)
{
    __shared__ float tile[64 * 65];
    const int z = blockIdx.z;
    const float* W = (z == 0) ? Wq : (z == 1) ? Wk : (z == 2) ? Wv : Wo;
    unsigned short* out = (z < 3) ? (Wt3 + (size_t)z * DIM * DIM) : Wto;
    const int k0 = blockIdx.x * 64, n0 = blockIdx.y * 64;
    const int t = threadIdx.x;
    const int r = t >> 2, c0 = (t & 3) * 16;
#pragma unroll
    for (int j = 0; j < 4; ++j) {
        float4 v = *(const float4*)&W[(size_t)(k0 + r) * DIM + n0 + c0 + j * 4];
        tile[r * 65 + c0 + j * 4 + 0] = v.x;
        tile[r * 65 + c0 + j * 4 + 1] = v.y;
        tile[r * 65 + c0 + j * 4 + 2] = v.z;
        tile[r * 65 + c0 + j * 4 + 3] = v.w;
    }
    __syncthreads();
    unsigned int p[8];
#pragma unroll
    for (int j = 0; j < 8; ++j)
        p[j] = pk2r(tile[(c0 + 2 * j) * 65 + r], tile[(c0 + 2 * j + 1) * 65 + r]);
    uint4 u0 = {p[0], p[1], p[2], p[3]}, u1 = {p[4], p[5], p[6], p[7]};
    unsigned short* dst = out + (size_t)(n0 + r) * DIM + k0 + c0;
    *(uint4*)dst = u0;
    *(uint4*)(dst + 8) = u1;
}

// ---------------------------------------------------------------------------
// QKV GEMM: 128x128, BK=32, dbuf single-barrier TWO-BODY K-loop (compile-time
// buffer index -> hoisted LDS addrs, running global pointers).
// Q/K: swapped operands -> packed uint2 stores.  V: transposed sigma layout.
// (XCD swizzle removed: R4 showed it cost ~12 us vs default order.)
// ---------------------------------------------------------------------------
__global__ __launch_bounds__(256)
void qkv_gemm(const unsigned short* __restrict__ Xbf,
              const unsigned short* __restrict__ Wt3,
              const float* __restrict__ bq, const float* __restrict__ bk,
              const float* __restrict__ bv,
              unsigned short* __restrict__ Qb,
              unsigned short* __restrict__ Kb,
              unsigned short* __restrict__ VbT)
{
    __shared__ unsigned short As[2][128 * 32];
    __shared__ unsigned short Bs[2][128 * 32];

    const int t = threadIdx.x, w = t >> 6, lane = t & 63;
    const int lm = lane & 15, grp = lane >> 4;
    const int wm = w >> 1, wn = w & 1;
    const int m0 = blockIdx.x * 128;
    const int mat = blockIdx.y >> 3;             // 0=Q 1=K 2=V
    const int n0 = (blockIdx.y & 7) * 128;
    const unsigned short* Bg = Wt3 + (size_t)mat * DIM * DIM;
    const int lr = lane >> 2, lc = (lane & 3) * 8;
    const int r0 = w * 16;
    const bool swap = (mat != 2);

    // running stage pointers (advance 32 elems per tile)
    const unsigned short* xs0 = Xbf + (size_t)(m0 + r0 + lr) * DIM + lc;
    const unsigned short* xs1 = Xbf + (size_t)(m0 + 64 + r0 + lr) * DIM + lc;
    const unsigned short* ws0 = Bg  + (size_t)(n0 + r0 + lr) * DIM + lc;
    const unsigned short* ws1 = Bg  + (size_t)(n0 + 64 + r0 + lr) * DIM + lc;

    // hoisted LDS fragment bases (per buffer)
    const unsigned short* afb[2];
    const unsigned short* bfb[2];
#pragma unroll
    for (int u = 0; u < 2; ++u) {
        afb[u] = &As[u][(wm * 64 + lm) * 32 + grp * 8];
        bfb[u] = &Bs[u][(wn * 64 + lm) * 32 + grp * 8];
    }

    floatx4 acc[4][4];
#pragma unroll
    for (int i = 0; i < 4; ++i)
#pragma unroll
        for (int j = 0; j < 4; ++j) acc[i][j] = (floatx4){0.f, 0.f, 0.f, 0.f};

#define QKV_STAGE(BUF) do {                                    \
        gll16(xs0, &As[BUF][r0 * 32]);                         \
        gll16(xs1, &As[BUF][(64 + r0) * 32]);                  \
        gll16(ws0, &Bs[BUF][r0 * 32]);                         \
        gll16(ws1, &Bs[BUF][(64 + r0) * 32]);                  \
        xs0 += 32; xs1 += 32; ws0 += 32; ws1 += 32;            \
    } while (0)

#define QKV_BODY(CUR) do {                                                    \
        __syncthreads();                                                      \
        QKV_STAGE(CUR ^ 1);                                                   \
        short8 af[4], bf[4];                                                  \
        _Pragma("unroll")                                                     \
        for (int mt = 0; mt < 4; ++mt)                                        \
            af[mt] = *(const short8*)(afb[CUR] + mt * 512);                   \
        _Pragma("unroll")                                                     \
        for (int nt = 0; nt < 4; ++nt)                                        \
            bf[nt] = *(const short8*)(bfb[CUR] + nt * 512);                   \
        if (swap) {                                                           \
            _Pragma("unroll")                                                 \
            for (int mt = 0; mt < 4; ++mt)                                    \
                _Pragma("unroll")                                             \
                for (int nt = 0; nt < 4; ++nt)                                \
                    acc[mt][nt] = __builtin_amdgcn_mfma_f32_16x16x32_bf16(    \
                        bf[nt], af[mt], acc[mt][nt], 0, 0, 0);                \
        } else {                                                              \
            _Pragma("unroll")                                                 \
            for (int mt = 0; mt < 4; ++mt)                                    \
                _Pragma("unroll")                                             \
                for (int nt = 0; nt < 4; ++nt)                                \
                    acc[mt][nt] = __builtin_amdgcn_mfma_f32_16x16x32_bf16(    \
                        af[mt], bf[nt], acc[mt][nt], 0, 0, 0);                \
        }                                                                     \
    } while (0)

    QKV_STAGE(0);
#pragma unroll 1
    for (int it = 0; it < DIM / 64; ++it) {   // 16 iterations x 2 bodies
        QKV_BODY(0);
        QKV_BODY(1);
    }
#undef QKV_BODY
#undef QKV_STAGE

    if (mat == 2) {          // V -> sigma-permuted + bank-swizzled [bh][d][s]
#pragma unroll
        for (int nt = 0; nt < 4; ++nt) {
            const int c = n0 + wn * 64 + nt * 16 + lm;
            const float bb = bv[c];
            const int h = c >> 6, d = c & 63;
#pragma unroll
            for (int mt = 0; mt < 4; ++mt) {
                const int r = m0 + wm * 64 + mt * 16 + grp * 4;
                const int b = r >> 11, s = r & 2047;
                const int si = s & 63, sb = s & ~63;
                const int cg = si >> 4, g = (si >> 2) & 3;
                const int unit = (((cg & 1) << 2) | g) ^ (d & 7);   // + bank XOR
                const int sph = sb + unit * 8 + ((cg >> 1) << 2);
                uint2 pv;
                pv.x = pk2r(acc[mt][nt][0] + bb, acc[mt][nt][1] + bb);
                pv.y = pk2r(acc[mt][nt][2] + bb, acc[mt][nt][3] + bb);
                *(uint2*)&VbT[(((size_t)(b * NHD + h)) * HD + d) * SEQ + sph] = pv;
            }
        }
    } else {                 // Q/K swapped epilogue: packed 4-channel stores
        const float* bias = (mat == 0) ? bq : bk;
        unsigned short* dst = (mat == 0) ? Qb : Kb;
        const float sc = (mat == 0) ? QSCALE : 1.0f;
#pragma unroll
        for (int nt = 0; nt < 4; ++nt) {
            const int c0 = n0 + wn * 64 + nt * 16 + grp * 4;   // 4 consecutive c
            float4 bb = *(const float4*)&bias[c0];
            const int h = c0 >> 6, d0 = c0 & 63;
#pragma unroll
            for (int mt = 0; mt < 4; ++mt) {
                const int r = m0 + wm * 64 + mt * 16 + lm;
                const int b = r >> 11, s = r & 2047;
                uint2 pv;
                pv.x = pk2r((acc[mt][nt][0] + bb.x) * sc, (acc[mt][nt][1] + bb.y) * sc);
                pv.y = pk2r((acc[mt][nt][2] + bb.z) * sc, (acc[mt][nt][3] + bb.w) * sc);
                const int dd = (mat == 0) ? d0
                             : ((((d0 >> 3) ^ (s & 7)) << 3) | (d0 & 7));
                *(uint2*)&dst[(((size_t)(b * NHD + h)) * SEQ + s) * HD + dd] = pv;
            }
        }
    }
}

// ---------------------------------------------------------------------------
// Flash attention v14: key-parity split -- halve LDS reads at CONSTANT
// occupancy.  256 thr / 4 waves: wave w = (qh = w>>1) q-half (32 rows) x
// (kh = w&1) key-parity (cg in {kh, 2+kh} = 32 of 64 keys).  Each K/V frag
// read feeds 2 q-groups -> per-wave ds_reads 16->8 KB/body, MFMA count
// unchanged (18/wave).  kh=0 uses v11's ap0/vba path, kh=1 the ap1/vbb path
// (sigma layout already splits cg parity into u-groups).  One-time epilogue
// cross-wave O/l combine through LDS aliased onto the K/V buffers.
// ---------------------------------------------------------------------------
__global__ __launch_bounds__(256, 4)
void attn(const unsigned short* __restrict__ Qb,
          const unsigned short* __restrict__ Kb,
          const unsigned short* __restrict__ VbT,
          const float* __restrict__ Pen,
          unsigned short* __restrict__ Cb)
{
    __shared__ __align__(16) char smem[32768];
    unsigned short (*Kt)[4096] = (unsigned short (*)[4096])smem;            // 2 x 8 KB
    unsigned short (*Vt)[4096] = (unsigned short (*)[4096])(smem + 16384);  // 2 x 8 KB
    float* Ep = (float*)smem;   // epilogue scratch (aliases Kt/Vt, post-loop)

    const int t = threadIdx.x, w = t >> 6, lane = t & 63;
    const int lm = lane & 15, grp = lane >> 4;
    const int x7 = lm & 7;
    const int qh = w >> 1, kh = w & 1;

    // XCD swizzle: each XCD gets 128 consecutive logical blocks = 4 heads.
    const int lin = blockIdx.y * (int)gridDim.x + blockIdx.x;   // 0..1023
    const int swz = (lin & 7) * ((SEQ / 64) * (BSZ * NHD) / 8) + (lin >> 3);
    const int bh = swz >> 5, b = bh >> 4, h = bh & 15;
    const int q0 = (swz & 31) * 64;

    // Q B-frags for both q-groups of this wave's q-half (n = q = lm, k = d)
    short8 qf[2][2];
#pragma unroll
    for (int qg = 0; qg < 2; ++qg) {
        const unsigned short* qrow =
            Qb + ((size_t)bh * SEQ + q0 + qh * 32 + qg * 16 + lm) * HD;
        qf[qg][0] = *(const short8*)(qrow + grp * 8);
        qf[qg][1] = *(const short8*)(qrow + 32 + grp * 8);
    }

    // all-ones bf16 B-frag for the l-sum MFMA
    const unsigned int one2 = 0x3f803f80u;
    uint4 onesu = {one2, one2, one2, one2};
    const short8 ones = *(const short8*)&onesu;

    floatx4 oacc[2][4];
#pragma unroll
    for (int qg = 0; qg < 2; ++qg)
#pragma unroll
        for (int i = 0; i < 4; ++i) oacc[qg][i] = (floatx4){0.f, 0.f, 0.f, 0.f};
    floatx4 lacc[2];
    lacc[0] = (floatx4){0.f, 0.f, 0.f, 0.f};
    lacc[1] = (floatx4){0.f, 0.f, 0.f, 0.f};

    const unsigned short* Kg = Kb + (size_t)bh * SEQ * HD;
    const unsigned short* Vg = VbT + (size_t)bh * HD * SEQ;
    const int srow = lane >> 3, scol = (lane & 7) * 8;   // gll16 lane mapping

    // running global prefetch pointers (each wave stages 16 rows of K and V)
    const unsigned short* kp0 = Kg + (size_t)(w * 16 + srow) * HD + scol;
    const unsigned short* kp1 = kp0 + 8 * HD;
    const unsigned short* vp0 = Vg + (size_t)(w * 16 + srow) * SEQ + scol;
    const unsigned short* vp1 = vp0 + 8 * SEQ;

    // stage tile 0 into buf 0
    gll16(kp0, &Kt[0][(w * 16) * 64]);
    gll16(kp1, &Kt[0][(w * 16 + 8) * 64]);
    gll16(vp0, &Vt[0][(w * 16) * 64]);
    gll16(vp1, &Vt[0][(w * 16 + 8) * 64]);
    kp0 += 64 * HD; kp1 += 64 * HD; vp0 += 64; vp1 += 64;

    // hoisted LDS fragment bases (per buffer), kh folded in:
    // K: two d-halves (a0/a1); cg = ci*2+kh -> +kh*1024, reads at +ci*2048.
    // V: parity u-group (kh? 4+grp : grp); reads at +dg*1024.
    const unsigned short* kba[2]; const unsigned short* kbb[2];
    const unsigned short* vbs[2];
#pragma unroll
    for (int u = 0; u < 2; ++u) {
        kba[u] = &Kt[u][lm * 64 + ((grp    ) ^ x7) * 8 + kh * 1024];
        kbb[u] = &Kt[u][lm * 64 + ((4 + grp) ^ x7) * 8 + kh * 1024];
        vbs[u] = &Vt[u][lm * 64 + (((kh ? 4 : 0) + grp) ^ x7) * 8];
    }
    const float* mp = Pen + (size_t)b * SEQ + kh * 16 + grp * 4;  // +64/body

#define ATTN_BODY(CUR) do {                                                   \
        __syncthreads();                                                      \
        float4 mdv[2];                                                        \
        mdv[0] = *(const float4*)(mp);                                        \
        mdv[1] = *(const float4*)(mp + 32);                                   \
        mp += 64;                                                             \
        __builtin_amdgcn_sched_barrier(0);                                    \
        gll16(kp0, &Kt[CUR ^ 1][(w * 16) * 64]);                              \
        gll16(kp1, &Kt[CUR ^ 1][(w * 16 + 8) * 64]);                          \
        gll16(vp0, &Vt[CUR ^ 1][(w * 16) * 64]);                              \
        gll16(vp1, &Vt[CUR ^ 1][(w * 16 + 8) * 64]);                          \
        kp0 += 64 * HD; kp1 += 64 * HD; vp0 += 64; vp1 += 64;                 \
        floatx4 sv[2][2];                                                     \
        __builtin_amdgcn_s_setprio(1);                                        \
        _Pragma("unroll")                                                     \
        for (int ci = 0; ci < 2; ++ci) {                                      \
            short8 a0 = *(const short8*)(kba[CUR] + ci * 2048);               \
            short8 a1 = *(const short8*)(kbb[CUR] + ci * 2048);               \
            floatx4 c0 = (floatx4){mdv[ci].x, mdv[ci].y, mdv[ci].z, mdv[ci].w}; \
            floatx4 t0 = __builtin_amdgcn_mfma_f32_16x16x32_bf16(a0, qf[0][0], c0, 0, 0, 0); \
            sv[0][ci]  = __builtin_amdgcn_mfma_f32_16x16x32_bf16(a1, qf[0][1], t0, 0, 0, 0); \
            floatx4 t1 = __builtin_amdgcn_mfma_f32_16x16x32_bf16(a0, qf[1][0], c0, 0, 0, 0); \
            sv[1][ci]  = __builtin_amdgcn_mfma_f32_16x16x32_bf16(a1, qf[1][1], t1, 0, 0, 0); \
        }                                                                     \
        __builtin_amdgcn_s_setprio(0);                                        \
        short8 vf[4];                                                         \
        _Pragma("unroll")                                                     \
        for (int dg = 0; dg < 4; ++dg)                                        \
            vf[dg] = *(const short8*)(vbs[CUR] + dg * 1024);                  \
        float p[2][2][4];                                                     \
        _Pragma("unroll")                                                     \
        for (int qg = 0; qg < 2; ++qg)                                        \
            _Pragma("unroll")                                                 \
            for (int ci = 0; ci < 2; ++ci) {                                  \
                p[qg][ci][0] = __builtin_exp2f(sv[qg][ci][0]);                \
                p[qg][ci][1] = __builtin_exp2f(sv[qg][ci][1]);                \
                p[qg][ci][2] = __builtin_exp2f(sv[qg][ci][2]);                \
                p[qg][ci][3] = __builtin_exp2f(sv[qg][ci][3]);                \
            }                                                                 \
        uint4 pu0, pu1;                                                       \
        pu0.x = cvtpk(p[0][0][0], p[0][0][1]); pu0.y = cvtpk(p[0][0][2], p[0][0][3]); \
        pu0.z = cvtpk(p[0][1][0], p[0][1][1]); pu0.w = cvtpk(p[0][1][2], p[0][1][3]); \
        pu1.x = cvtpk(p[1][0][0], p[1][0][1]); pu1.y = cvtpk(p[1][0][2], p[1][0][3]); \
        pu1.z = cvtpk(p[1][1][0], p[1][1][1]); pu1.w = cvtpk(p[1][1][2], p[1][1][3]); \
        short8 ap0 = *(const short8*)&pu0;                                    \
        short8 ap1 = *(const short8*)&pu1;                                    \
        __builtin_amdgcn_s_setprio(1);                                        \
        _Pragma("unroll")                                                     \
        for (int dg = 0; dg < 4; ++dg) {                                      \
            oacc[0][dg] = __builtin_amdgcn_mfma_f32_16x16x32_bf16(ap0, vf[dg], oacc[0][dg], 0, 0, 0); \
            oacc[1][dg] = __builtin_amdgcn_mfma_f32_16x16x32_bf16(ap1, vf[dg], oacc[1][dg], 0, 0, 0); \
        }                                                                     \
        lacc[0] = __builtin_amdgcn_mfma_f32_16x16x32_bf16(ap0, ones, lacc[0], 0, 0, 0); \
        lacc[1] = __builtin_amdgcn_mfma_f32_16x16x32_bf16(ap1, ones, lacc[1], 0, 0, 0); \
        __builtin_amdgcn_s_setprio(0);                                        \
    } while (0)

#pragma unroll 1
    for (int it = 0; it < SEQ / 128; ++it) {   // 16 iterations x 2 bodies
        ATTN_BODY(0);
        ATTN_BODY(1);
    }
#undef ATTN_BODY

    // ---- epilogue: combine kh=0 / kh=1 partials through LDS ----
    // (barrier drains last prefetch gll16 writes before we alias the pool)
    __syncthreads();
    if (kh) {
        float* Eo = Ep + qh * 2048;
        float* El = Ep + 4096 + qh * 512;
#pragma unroll
        for (int qg = 0; qg < 2; ++qg) {
#pragma unroll
            for (int dg = 0; dg < 4; ++dg)
#pragma unroll
                for (int r = 0; r < 4; ++r)
                    Eo[((qg * 4 + dg) * 16 + grp * 4 + r) * 16 + lm] = oacc[qg][dg][r];
#pragma unroll
            for (int r = 0; r < 4; ++r)
                El[(qg * 16 + grp * 4 + r) * 16 + lm] = lacc[qg][r];
        }
    }
    __syncthreads();
    if (!kh) {
        float* Eo = Ep + qh * 2048;
        float* El = Ep + 4096 + qh * 512;
#pragma unroll
        for (int qg = 0; qg < 2; ++qg) {
            float inv[4];
#pragma unroll
            for (int r = 0; r < 4; ++r) {
                const float lt = lacc[qg][r] + El[(qg * 16 + grp * 4 + r) * 16 + lm];
                inv[r] = (lt > 0.f) ? 1.0f / lt : 0.f;
            }
#pragma unroll
            for (int dg = 0; dg < 4; ++dg)
#pragma unroll
                for (int r = 0; r < 4; ++r) {
                    const float o = oacc[qg][dg][r] +
                        Eo[((qg * 4 + dg) * 16 + grp * 4 + r) * 16 + lm];
                    const int s = q0 + qh * 32 + qg * 16 + grp * 4 + r;
                    Cb[((size_t)(b * SEQ + s)) * DIM + h * HD + dg * 16 + lm] =
                        f2bf(o * inv[r]);
                }
        }
    }
}

// ---------------------------------------------------------------------------
// out = ctx @ Wo + bo: 128Mx64N, dbuf two-body K-loop, swapped operands,
// float4 stores.  (XCD swizzle removed: R4 regression.)
// ---------------------------------------------------------------------------
__global__ __launch_bounds__(256)
void out_gemm(const unsigned short* __restrict__ Cb,
              const unsigned short* __restrict__ Wto,
              const float* __restrict__ bo,
              float* __restrict__ out)
{
    __shared__ unsigned short As[2][128 * 32];
    __shared__ unsigned short Bs[2][64 * 32];

    const int t = threadIdx.x, w = t >> 6, lane = t & 63;
    const int lm = lane & 15, grp = lane >> 4;
    const int m0 = blockIdx.x * 128;
    const int n0 = blockIdx.y * 64;
    const int lr = lane >> 2, lc = (lane & 3) * 8;
    const int r0 = w * 16;

    const unsigned short* cs0 = Cb  + (size_t)(m0 + r0 + lr) * DIM + lc;
    const unsigned short* cs1 = Cb  + (size_t)(m0 + 64 + r0 + lr) * DIM + lc;
    const unsigned short* ws0 = Wto + (size_t)(n0 + r0 + lr) * DIM + lc;

    const unsigned short* afb[2];
    const unsigned short* bfb[2];
#pragma unroll
    for (int u = 0; u < 2; ++u) {
        afb[u] = &As[u][(w * 32 + lm) * 32 + grp * 8];
        bfb[u] = &Bs[u][lm * 32 + grp * 8];
    }

    floatx4 acc[2][4];
#pragma unroll
    for (int i = 0; i < 2; ++i)
#pragma unroll
        for (int j = 0; j < 4; ++j) acc[i][j] = (floatx4){0.f, 0.f, 0.f, 0.f};

#define OUT_STAGE(BUF) do {                                    \
        gll16(cs0, &As[BUF][r0 * 32]);                         \
        gll16(cs1, &As[BUF][(64 + r0) * 32]);                  \
        gll16(ws0, &Bs[BUF][r0 * 32]);                         \
        cs0 += 32; cs1 += 32; ws0 += 32;                       \
    } while (0)

#define OUT_BODY(CUR) do {                                                    \
        __syncthreads();                                                      \
        OUT_STAGE(CUR ^ 1);                                                   \
        short8 af[2], bf[4];                                                  \
        _Pragma("unroll")                                                     \
        for (int mt = 0; mt < 2; ++mt)                                        \
            af[mt] = *(const short8*)(afb[CUR] + mt * 512);                   \
        _Pragma("unroll")                                                     \
        for (int nt = 0; nt < 4; ++nt)                                        \
            bf[nt] = *(const short8*)(bfb[CUR] + nt * 512);                   \
        _Pragma("unroll")                                                     \
        for (int mt = 0; mt < 2; ++mt)                                        \
            _Pragma("unroll")                                                 \
            for (int nt = 0; nt < 4; ++nt)                                    \
                acc[mt][nt] = __builtin_amdgcn_mfma_f32_16x16x32_bf16(        \
                    bf[nt], af[mt], acc[mt][nt], 0, 0, 0);                    \
    } while (0)

    OUT_STAGE(0);
#pragma unroll 1
    for (int it = 0; it < DIM / 64; ++it) {
        OUT_BODY(0);
        OUT_BODY(1);
    }
#undef OUT_BODY
#undef OUT_STAGE

#pragma unroll
    for (int nt = 0; nt < 4; ++nt) {
        const int c0 = n0 + nt * 16 + grp * 4;
        float4 bb = *(const float4*)&bo[c0];
#pragma unroll
        for (int mt = 0; mt < 2; ++mt) {
            const int r = m0 + w * 32 + mt * 16 + lm;
            float4 o = {acc[mt][nt][0] + bb.x, acc[mt][nt][1] + bb.y,
                        acc[mt][nt][2] + bb.z, acc[mt][nt][3] + bb.w};
            *(float4*)&out[(size_t)r * DIM + c0] = o;
        }
    }
}

// ---------------------------------------------------------------------------
extern "C" void kernel_launch(void* const* d_in, const int* in_sizes, int n_in,
                              void* d_out, int out_size, void* d_ws, size_t ws_size,
                              hipStream_t stream)
{
    const float* x    = (const float*)d_in[0];
    const float* mask = (const float*)d_in[1];
    const float* Wq   = (const float*)d_in[2];
    const float* bq   = (const float*)d_in[3];
    const float* Wk   = (const float*)d_in[4];
    const float* bk   = (const float*)d_in[5];
    const float* Wv   = (const float*)d_in[6];
    const float* bv   = (const float*)d_in[7];
    const float* Wo   = (const float*)d_in[8];
    const float* bo   = (const float*)d_in[9];
    float* out = (float*)d_out;

    const size_t M1 = (size_t)DIM * DIM;           // 1M elems
    unsigned short* Qb  = (unsigned short*)d_ws;   // 4M elems each
    unsigned short* Kb  = Qb  + 4 * M1;
    unsigned short* VbT = Kb  + 4 * M1;
    unsigned short* Cb  = VbT + 4 * M1;
    unsigned short* Xbf = Cb  + 4 * M1;
    unsigned short* Wt3 = Xbf + 4 * M1;            // 3M elems
    unsigned short* Wto = Wt3 + 3 * M1;            // 1M elems  (48 MB total)
    float*          Pen = (float*)(Wto + M1);      // MTOT floats (16 KB)

    conv_x <<<dim3((MTOT * DIM) / 2048), 256, 0, stream>>>(x, mask, Xbf, Pen);
    conv_wt<<<dim3(16, 16, 4), 256, 0, stream>>>(Wq, Wk, Wv, Wo, Wt3, Wto);
    qkv_gemm<<<dim3(MTOT / 128, 24), 256, 0, stream>>>(Xbf, Wt3, bq, bk, bv, Qb, Kb, VbT);
    attn<<<dim3(SEQ / 64, BSZ * NHD), 256, 0, stream>>>(Qb, Kb, VbT, Pen, Cb);
    out_gemm<<<dim3(MTOT / 128, DIM / 64), 256, 0, stream>>>(Cb, Wto, bo, out);
}